// Round 3
// baseline (232.344 us; speedup 1.0000x reference)
//
#include <hip/hip_runtime.h>
#include <math.h>

#define N_POINTS   32768
#define BLOCK      256
#define P          8                            // a-points per thread
#define ROWS_PER_BLOCK (P * BLOCK)              // 2048
#define ROW_BLOCKS (N_POINTS / ROWS_PER_BLOCK)  // 16
#define S          32                           // b-dimension splits
#define CHUNK_B    (N_POINTS / S)               // 1024 b-points staged per block
#define NB         4                            // columns per compute batch

// 4 cols x 8 rows batch: 96 FMA + 16 min3 = 112 VALU insts for 32 pairs
#define COMPUTE(Bf)                                                                              \
    _Pragma("unroll")                                                                            \
    for (int p = 0; p < P; ++p) {                                                                \
        float t0 = fmaf(naz[p], Bf[0].z, fmaf(nay[p], Bf[0].y, fmaf(nax[p], Bf[0].x, Bf[0].w))); \
        float t1 = fmaf(naz[p], Bf[1].z, fmaf(nay[p], Bf[1].y, fmaf(nax[p], Bf[1].x, Bf[1].w))); \
        float t2 = fmaf(naz[p], Bf[2].z, fmaf(nay[p], Bf[2].y, fmaf(nax[p], Bf[2].x, Bf[2].w))); \
        float t3 = fmaf(naz[p], Bf[3].z, fmaf(nay[p], Bf[3].y, fmaf(nax[p], Bf[3].x, Bf[3].w))); \
        m[p] = fminf(fminf(m[p], t0), t1);  /* -> v_min3_f32 */                                  \
        m[p] = fminf(fminf(m[p], t2), t3);  /* -> v_min3_f32 */                                  \
    }

// refill a register batch 2 batches ahead; mask makes tail prefetch harmless
#define PREFETCH(Bf, base)                                                                       \
    _Pragma("unroll")                                                                            \
    for (int q = 0; q < NB; ++q) Bf[q] = bs[((base) + q) & (CHUNK_B - 1)];

// ---------------------------------------------------------------------------
// Kernel 1: block (dir, rb, sb): for each of its 2048 a-points, min over its
// 1024-point b-chunk of (||b||^2 - 2 a.b); ||a||^2 re-added at the write.
// Inner loop is software-pipelined with 2 register batches so the ds_read ->
// FMA distance is ~224 cycles (no lgkm stalls even single-wave).
// ---------------------------------------------------------------------------
__global__ __launch_bounds__(BLOCK, 4) void chamfer_partial_kernel(
    const float* __restrict__ target,
    const float* __restrict__ outp,
    float* __restrict__ partial)   // [S][2*N_POINTS]
{
    const int bid = blockIdx.x;
    const int dir = bid >> 9;          // / (ROW_BLOCKS*S) = /512
    const int rem = bid & 511;
    const int rb  = rem >> 5;          // / S
    const int sb  = rem & (S - 1);

    const float* __restrict__ a = dir ? outp   : target;
    const float* __restrict__ b = dir ? target : outp;

    __shared__ float4 bs[CHUNK_B];     // (x, y, z, ||b||^2) : 16 KB

    // ---- stage b chunk into LDS ----
    const int b_base = sb * CHUNK_B;
    #pragma unroll
    for (int k = 0; k < CHUNK_B / BLOCK; ++k) {
        const int j = threadIdx.x + k * BLOCK;
        const float* bp = &b[(size_t)(b_base + j) * 3];
        const float bx = bp[0], by = bp[1], bz = bp[2];
        bs[j] = make_float4(bx, by, bz, bx * bx + by * by + bz * bz);
    }

    // ---- load my P a-points, precompute -2a and ||a||^2 ----
    float nax[P], nay[P], naz[P], an[P], m[P];
    const int a_base = rb * ROWS_PER_BLOCK + threadIdx.x;
    #pragma unroll
    for (int p = 0; p < P; ++p) {
        const float* ap = &a[(size_t)(a_base + p * BLOCK) * 3];
        const float ax = ap[0], ay = ap[1], az = ap[2];
        nax[p] = -2.0f * ax;
        nay[p] = -2.0f * ay;
        naz[p] = -2.0f * az;
        an[p]  = ax * ax + ay * ay + az * az;
        m[p]   = 3.4e38f;
    }

    __syncthreads();

    // ---- software-pipelined main loop ----
    float4 A0[NB], B0[NB];
    #pragma unroll
    for (int q = 0; q < NB; ++q) { A0[q] = bs[q]; B0[q] = bs[NB + q]; }

    for (int j = 0; j < CHUNK_B; j += 2 * NB) {
        COMPUTE(A0)
        PREFETCH(A0, j + 2 * NB)
        COMPUTE(B0)
        PREFETCH(B0, j + 3 * NB)
    }

    // ---- write partial mins (+ ||a||^2 re-added) ----
    #pragma unroll
    for (int p = 0; p < P; ++p) {
        partial[(size_t)sb * (2 * N_POINTS) + dir * N_POINTS +
                rb * ROWS_PER_BLOCK + p * BLOCK + threadIdx.x] = m[p] + an[p];
    }
}

// ---------------------------------------------------------------------------
// Kernel 2: min over the S partials per point, sqrt, block-level partial sums.
// ---------------------------------------------------------------------------
__global__ __launch_bounds__(256) void chamfer_reduce_kernel(
    const float* __restrict__ partial,  // [S][2*N_POINTS]
    float* __restrict__ bsums)          // [64]
{
    const int c0 = blockIdx.x * 1024 + threadIdx.x;
    float sum = 0.0f;
    #pragma unroll
    for (int k = 0; k < 4; ++k) {
        const int c = c0 + k * 256;
        float mn = 3.4e38f;
        #pragma unroll
        for (int s = 0; s < S; ++s)
            mn = fminf(mn, partial[(size_t)s * (2 * N_POINTS) + c]);
        sum += sqrtf(fmaxf(mn, 0.0f));   // clamp: expanded form can go ~-1e-7
    }

    __shared__ float red[256];
    red[threadIdx.x] = sum;
    __syncthreads();
    #pragma unroll
    for (int off = 128; off > 0; off >>= 1) {
        if (threadIdx.x < off) red[threadIdx.x] += red[threadIdx.x + off];
        __syncthreads();
    }
    if (threadIdx.x == 0) bsums[blockIdx.x] = red[0];
}

// ---------------------------------------------------------------------------
// Kernel 3: final scalar. loss = (sum_all_sqrt / (2N)) * 10 / 1.02^(cur//20)
// ---------------------------------------------------------------------------
__global__ void chamfer_finalize_kernel(
    const float* __restrict__ bsums,    // [64]
    const int* __restrict__ curp,
    float* __restrict__ out)
{
    float v = bsums[threadIdx.x];       // 64 threads, one per block sum
    #pragma unroll
    for (int off = 32; off > 0; off >>= 1)
        v += __shfl_down(v, off);
    if (threadIdx.x == 0) {
        const int cur = curp[0];
        const float decay = powf(1.02f, (float)(cur / 20));
        out[0] = v / (float)(2 * N_POINTS) * 10.0f / decay;
    }
}

// ---------------------------------------------------------------------------
extern "C" void kernel_launch(void* const* d_in, const int* in_sizes, int n_in,
                              void* d_out, int out_size, void* d_ws, size_t ws_size,
                              hipStream_t stream) {
    const float* target = (const float*)d_in[0];
    const float* outp   = (const float*)d_in[1];
    const int*   cur    = (const int*)d_in[2];
    float*       out    = (float*)d_out;

    float* partial = (float*)d_ws;                         // S * 2N floats = 8.4 MB
    float* bsums   = partial + (size_t)S * 2 * N_POINTS;   // 64 floats

    chamfer_partial_kernel<<<2 * ROW_BLOCKS * S, BLOCK, 0, stream>>>(target, outp, partial);
    chamfer_reduce_kernel<<<64, 256, 0, stream>>>(partial, bsums);
    chamfer_finalize_kernel<<<1, 64, 0, stream>>>(bsums, cur, out);
}

// Round 4
// 202.003 us; speedup vs baseline: 1.1502x; 1.1502x over previous
//
#include <hip/hip_runtime.h>
#include <math.h>

#define NPTS 32768
#define G    20
#define NC   (G*G*G)            // 8000 cells
#define INVH 18.18181818f       // G / 1.1  (domain [0,1.1] covers target and output)
#define H    0.055f             // 1.1 / G (float 0.055f < true 1/INVH -> conservative bound)

// Same cell mapping EVERYWHERE (hist, scatter, query) -> exactness argument holds.
__device__ __forceinline__ int cell1(float v) {
    int c = (int)(v * INVH);
    c = c < 0 ? 0 : c;
    return c > (G - 1) ? (G - 1) : c;
}

// ---------------------------------------------------------------------------
__global__ __launch_bounds__(256) void zero_kernel(int* __restrict__ cnt) {
    int i = blockIdx.x * 256 + threadIdx.x;
    if (i < 2 * NC) cnt[i] = 0;
}

// ---------------------------------------------------------------------------
__global__ __launch_bounds__(256) void hist_kernel(const float* __restrict__ target,
                                                   const float* __restrict__ outp,
                                                   int* __restrict__ cnt) {
    int i = blockIdx.x * 256 + threadIdx.x;          // 0..65535
    int cloud = i >> 15, pi = i & (NPTS - 1);
    const float* P = cloud ? outp : target;
    float x = P[3 * pi], y = P[3 * pi + 1], z = P[3 * pi + 2];
    int cid = (cell1(z) * G + cell1(y)) * G + cell1(x);
    atomicAdd(&cnt[cloud * NC + cid], 1);
}

// ---------------------------------------------------------------------------
// One block per cloud. Exclusive scan of cnt -> desc{start,count} and cursor.
__global__ __launch_bounds__(1024) void scan_kernel(const int* __restrict__ cnt,
                                                    int2* __restrict__ desc,
                                                    int* __restrict__ cursor) {
    const int* c = cnt + blockIdx.x * NC;
    int2* dc = desc + blockIdx.x * NC;
    int* cur = cursor + blockIdx.x * NC;
    __shared__ int sh[1024];
    int carry = 0;
    for (int t = 0; t < (NC + 1023) / 1024; ++t) {
        int idx = t * 1024 + threadIdx.x;
        int v = (idx < NC) ? c[idx] : 0;
        __syncthreads();                 // protect sh from previous tile's reads
        sh[threadIdx.x] = v;
        __syncthreads();
        #pragma unroll
        for (int off = 1; off < 1024; off <<= 1) {   // Hillis-Steele inclusive
            int add = (threadIdx.x >= off) ? sh[threadIdx.x - off] : 0;
            __syncthreads();
            sh[threadIdx.x] += add;
            __syncthreads();
        }
        int incl  = sh[threadIdx.x];
        int total = sh[1023];
        if (idx < NC) {
            int st = carry + incl - v;   // exclusive
            dc[idx]  = make_int2(st, v);
            cur[idx] = st;
        }
        carry += total;
    }
}

// ---------------------------------------------------------------------------
__global__ __launch_bounds__(256) void scatter_kernel(const float* __restrict__ target,
                                                      const float* __restrict__ outp,
                                                      int* __restrict__ cursor,
                                                      float4* __restrict__ sortedT,
                                                      float4* __restrict__ sortedO) {
    int i = blockIdx.x * 256 + threadIdx.x;
    int cloud = i >> 15, pi = i & (NPTS - 1);
    const float* P = cloud ? outp : target;
    float x = P[3 * pi], y = P[3 * pi + 1], z = P[3 * pi + 2];
    int cid = (cell1(z) * G + cell1(y)) * G + cell1(x);
    int pos = atomicAdd(&cursor[cloud * NC + cid], 1);
    float4* S = cloud ? sortedO : sortedT;
    S[pos] = make_float4(x, y, z, 0.0f);
}

// ---------------------------------------------------------------------------
// One thread per query point (both directions: 65536). Queries come from the
// cell-sorted arrays -> lanes in a wave sit in the same/adjacent cells (low
// divergence, shared L1 lines on candidates). Expanding Chebyshev shells;
// exact termination: all unsearched points are > R*H away once shell R done.
__global__ __launch_bounds__(256) void query_kernel(const float4* __restrict__ sortedT,
                                                    const float4* __restrict__ sortedO,
                                                    const int2* __restrict__ desc,
                                                    float* __restrict__ bsums) {
    int i = blockIdx.x * 256 + threadIdx.x;
    int dir = i >> 15, qi = i & (NPTS - 1);
    const float4* A = dir ? sortedO : sortedT;   // queries
    const float4* B = dir ? sortedT : sortedO;   // candidates
    const int2* descB = desc + (dir ^ 1) * NC;

    float4 q = A[qi];
    int cx = cell1(q.x), cy = cell1(q.y), cz = cell1(q.z);
    float best = 3.4e38f;

    for (int R = 0; R < G; ++R) {
        int zlo = cz - R < 0 ? 0 : cz - R, zhi = cz + R > G - 1 ? G - 1 : cz + R;
        int ylo = cy - R < 0 ? 0 : cy - R, yhi = cy + R > G - 1 ? G - 1 : cy + R;
        int xlo = cx - R < 0 ? 0 : cx - R, xhi = cx + R > G - 1 ? G - 1 : cx + R;
        for (int zz = zlo; zz <= zhi; ++zz) {
            int adz = zz - cz; adz = adz < 0 ? -adz : adz;
            for (int yy = ylo; yy <= yhi; ++yy) {
                int ady = yy - cy; ady = ady < 0 ? -ady : ady;
                for (int xx = xlo; xx <= xhi; ++xx) {
                    int adx = xx - cx; adx = adx < 0 ? -adx : adx;
                    int amax = adx > ady ? adx : ady;
                    amax = amax > adz ? amax : adz;
                    if (amax != R) continue;          // shell only (no rescan)
                    int2 dcn = descB[(zz * G + yy) * G + xx];
                    int s = dcn.x, n = dcn.y;
                    int k = 0;
                    for (; k + 2 <= n; k += 2) {      // 2-way ILP
                        float4 p0 = B[s + k], p1 = B[s + k + 1];
                        float dx0 = q.x - p0.x, dy0 = q.y - p0.y, dz0 = q.z - p0.z;
                        float dx1 = q.x - p1.x, dy1 = q.y - p1.y, dz1 = q.z - p1.z;
                        float d0 = fmaf(dz0, dz0, fmaf(dy0, dy0, dx0 * dx0));
                        float d1 = fmaf(dz1, dz1, fmaf(dy1, dy1, dx1 * dx1));
                        best = fminf(fminf(best, d0), d1);
                    }
                    if (k < n) {
                        float4 p0 = B[s + k];
                        float dx0 = q.x - p0.x, dy0 = q.y - p0.y, dz0 = q.z - p0.z;
                        best = fminf(best, fmaf(dz0, dz0, fmaf(dy0, dy0, dx0 * dx0)));
                    }
                }
            }
        }
        float rh = (float)R * H;
        if (best <= rh * rh) break;   // nothing unsearched can beat best
    }

    float sv = sqrtf(best);
    __shared__ float red[256];
    red[threadIdx.x] = sv;
    __syncthreads();
    #pragma unroll
    for (int off = 128; off > 0; off >>= 1) {
        if (threadIdx.x < off) red[threadIdx.x] += red[threadIdx.x + off];
        __syncthreads();
    }
    if (threadIdx.x == 0) bsums[blockIdx.x] = red[0];
}

// ---------------------------------------------------------------------------
__global__ __launch_bounds__(256) void finalize_kernel(const float* __restrict__ bsums,
                                                       const int* __restrict__ curp,
                                                       float* __restrict__ out) {
    __shared__ float red[256];
    red[threadIdx.x] = bsums[threadIdx.x];
    __syncthreads();
    #pragma unroll
    for (int off = 128; off > 0; off >>= 1) {
        if (threadIdx.x < off) red[threadIdx.x] += red[threadIdx.x + off];
        __syncthreads();
    }
    if (threadIdx.x == 0) {
        float decay = powf(1.02f, (float)(curp[0] / 20));
        out[0] = red[0] / 65536.0f * 10.0f / decay;
    }
}

// ---------------------------------------------------------------------------
extern "C" void kernel_launch(void* const* d_in, const int* in_sizes, int n_in,
                              void* d_out, int out_size, void* d_ws, size_t ws_size,
                              hipStream_t stream) {
    const float* target = (const float*)d_in[0];
    const float* outp   = (const float*)d_in[1];
    const int*   cur    = (const int*)d_in[2];
    float*       out    = (float*)d_out;

    // ws layout (~1.26 MB): sortedT | sortedO | cnt | cursor | desc | bsums
    float4* sortedT = (float4*)d_ws;
    float4* sortedO = sortedT + NPTS;
    int*    cnt     = (int*)(sortedO + NPTS);
    int*    cursor  = cnt + 2 * NC;
    int2*   desc    = (int2*)(cursor + 2 * NC);
    float*  bsums   = (float*)(desc + 2 * NC);

    zero_kernel<<<(2 * NC + 255) / 256, 256, 0, stream>>>(cnt);
    hist_kernel<<<256, 256, 0, stream>>>(target, outp, cnt);
    scan_kernel<<<2, 1024, 0, stream>>>(cnt, desc, cursor);
    scatter_kernel<<<256, 256, 0, stream>>>(target, outp, cursor, sortedT, sortedO);
    query_kernel<<<256, 256, 0, stream>>>(sortedT, sortedO, desc, bsums);
    finalize_kernel<<<1, 256, 0, stream>>>(bsums, cur, out);
}

// Round 5
// 113.227 us; speedup vs baseline: 2.0520x; 1.7841x over previous
//
#include <hip/hip_runtime.h>
#include <math.h>

#define NPTS 32768
#define G    20
#define NC   (G*G*G)            // 8000 cells
#define INVH 18.18181818f       // G / 1.1 (domain [0,1.1] covers target and output)
#define H    0.0548f            // conservative < 1/INVH = 0.055: termination bound stays exact

// Same cell mapping EVERYWHERE (hist, scatter, query) -> exactness argument holds.
__device__ __forceinline__ int cell1(float v) {
    int c = (int)(v * INVH);
    c = c < 0 ? 0 : c;
    return c > (G - 1) ? (G - 1) : c;
}

// min-dist over contiguous candidate range [s,e) (2-way ILP)
__device__ __forceinline__ float scan_range(const float4* __restrict__ B, int s, int e,
                                            float qx, float qy, float qz, float mn) {
    int k = s;
    for (; k + 2 <= e; k += 2) {
        float4 p0 = B[k], p1 = B[k + 1];
        float dx0 = qx - p0.x, dy0 = qy - p0.y, dz0 = qz - p0.z;
        float dx1 = qx - p1.x, dy1 = qy - p1.y, dz1 = qz - p1.z;
        float d0 = fmaf(dz0, dz0, fmaf(dy0, dy0, dx0 * dx0));
        float d1 = fmaf(dz1, dz1, fmaf(dy1, dy1, dx1 * dx1));
        mn = fminf(fminf(mn, d0), d1);
    }
    if (k < e) {
        float4 p0 = B[k];
        float dx0 = qx - p0.x, dy0 = qy - p0.y, dz0 = qz - p0.z;
        mn = fminf(mn, fmaf(dz0, dz0, fmaf(dy0, dy0, dx0 * dx0)));
    }
    return mn;
}

// ---------------------------------------------------------------------------
__global__ __launch_bounds__(256) void zero_kernel(int* __restrict__ cnt) {
    int i = blockIdx.x * 256 + threadIdx.x;
    if (i < 2 * NC) cnt[i] = 0;
}

// ---------------------------------------------------------------------------
__global__ __launch_bounds__(256) void hist_kernel(const float* __restrict__ target,
                                                   const float* __restrict__ outp,
                                                   int* __restrict__ cnt) {
    int i = blockIdx.x * 256 + threadIdx.x;          // 0..65535
    int cloud = i >> 15, pi = i & (NPTS - 1);
    const float* P = cloud ? outp : target;
    float x = P[3 * pi], y = P[3 * pi + 1], z = P[3 * pi + 2];
    int cid = (cell1(z) * G + cell1(y)) * G + cell1(x);
    atomicAdd(&cnt[cloud * NC + cid], 1);
}

// ---------------------------------------------------------------------------
// One block per cloud. Wave-shfl exclusive scan (2 barriers per 1024-tile).
__global__ __launch_bounds__(1024) void scan_kernel(const int* __restrict__ cnt,
                                                    int2* __restrict__ desc,
                                                    int* __restrict__ cursor) {
    const int* c = cnt + blockIdx.x * NC;
    int2* dc = desc + blockIdx.x * NC;
    int* cur = cursor + blockIdx.x * NC;
    const int lane = threadIdx.x & 63;
    const int wid  = threadIdx.x >> 6;               // 0..15
    __shared__ int wtot[16];
    __shared__ int tile_total_sh;
    int carry = 0;
    for (int t0 = 0; t0 < NC; t0 += 1024) {
        const int idx = t0 + threadIdx.x;
        const int v = (idx < NC) ? c[idx] : 0;
        int val = v;                                  // wave inclusive scan
        #pragma unroll
        for (int off = 1; off < 64; off <<= 1) {
            int tmp = __shfl_up(val, off, 64);
            if (lane >= off) val += tmp;
        }
        if (lane == 63) wtot[wid] = val;
        __syncthreads();
        if (threadIdx.x == 0) {                       // scan 16 wave totals
            int acc = 0;
            #pragma unroll
            for (int w = 0; w < 16; ++w) { int x = wtot[w]; wtot[w] = acc; acc += x; }
            tile_total_sh = acc;
        }
        __syncthreads();
        const int excl = carry + wtot[wid] + (val - v);
        if (idx < NC) { dc[idx] = make_int2(excl, v); cur[idx] = excl; }
        carry += tile_total_sh;
        __syncthreads();                              // protect wtot for next tile
    }
}

// ---------------------------------------------------------------------------
__global__ __launch_bounds__(256) void scatter_kernel(const float* __restrict__ target,
                                                      const float* __restrict__ outp,
                                                      int* __restrict__ cursor,
                                                      float4* __restrict__ sortedT,
                                                      float4* __restrict__ sortedO) {
    int i = blockIdx.x * 256 + threadIdx.x;
    int cloud = i >> 15, pi = i & (NPTS - 1);
    const float* P = cloud ? outp : target;
    float x = P[3 * pi], y = P[3 * pi + 1], z = P[3 * pi + 2];
    int cid = (cell1(z) * G + cell1(y)) * G + cell1(x);
    int pos = atomicAdd(&cursor[cloud * NC + cid], 1);
    float4* S = cloud ? sortedO : sortedT;
    S[pos] = make_float4(x, y, z, 0.0f);
}

// ---------------------------------------------------------------------------
// 16 lanes per query; lanes 0..8 scan the 9 contiguous (z,y)-row ranges of the
// 3x3x3 neighborhood in PARALLEL (x-neighbors are contiguous in the sorted
// array), then shfl_xor width-16 min-reduce. Exact fallback: expanding
// Chebyshev shells, rows spread over the 16 lanes; unsearched points beyond
// shell R are provably > R*H away.
__global__ __launch_bounds__(256) void query_kernel(const float4* __restrict__ sortedT,
                                                    const float4* __restrict__ sortedO,
                                                    const int2* __restrict__ desc,
                                                    float* __restrict__ bsums) {
    const int t = blockIdx.x * 256 + threadIdx.x;
    const int gq = t >> 4;                 // global query id 0..65535
    const int r  = t & 15;                 // lane within group
    const int dir = gq >> 15;
    const int qi  = gq & (NPTS - 1);
    const float4* A = dir ? sortedO : sortedT;   // queries
    const float4* B = dir ? sortedT : sortedO;   // candidates
    const int2* descB = desc + (dir ^ 1) * NC;

    const float4 q = A[qi];
    const int cx = cell1(q.x), cy = cell1(q.y), cz = cell1(q.z);
    const int xlo1 = cx > 0 ? cx - 1 : 0;
    const int xhi1 = cx < G - 1 ? cx + 1 : G - 1;

    float rowmin = 3.4e38f;
    if (r < 9) {
        const int zz = cz + r / 3 - 1;
        const int yy = cy + r % 3 - 1;
        if (zz >= 0 && zz < G && yy >= 0 && yy < G) {
            const int base = (zz * G + yy) * G;
            const int2 dlo = descB[base + xlo1];
            const int2 dhi = descB[base + xhi1];
            rowmin = scan_range(B, dlo.x, dhi.x + dhi.y, q.x, q.y, q.z, rowmin);
        }
    }
    float best = rowmin;
    #pragma unroll
    for (int off = 8; off; off >>= 1) best = fminf(best, __shfl_xor(best, off, 16));

    if (best > H * H) {                    // rare: not provably done after 3x3x3
        for (int R = 2; R < G; ++R) {
            float smin = 3.4e38f;
            const int W = 2 * R + 1;
            for (int idx = r; idx < W * W; idx += 16) {
                const int dz = idx / W - R, dy = idx % W - R;
                const int zz = cz + dz, yy = cy + dy;
                if (zz < 0 || zz >= G || yy < 0 || yy >= G) continue;
                const int base = (zz * G + yy) * G;
                const int adz = dz < 0 ? -dz : dz, ady = dy < 0 ? -dy : dy;
                if ((adz > ady ? adz : ady) == R) {   // perimeter row: full x-range
                    const int xl = cx - R < 0 ? 0 : cx - R;
                    const int xh = cx + R > G - 1 ? G - 1 : cx + R;
                    const int2 dlo = descB[base + xl];
                    const int2 dhi = descB[base + xh];
                    smin = scan_range(B, dlo.x, dhi.x + dhi.y, q.x, q.y, q.z, smin);
                } else {                              // interior row: two edge cells
                    if (cx - R >= 0) {
                        const int2 d0 = descB[base + cx - R];
                        smin = scan_range(B, d0.x, d0.x + d0.y, q.x, q.y, q.z, smin);
                    }
                    if (cx + R <= G - 1) {
                        const int2 d1 = descB[base + cx + R];
                        smin = scan_range(B, d1.x, d1.x + d1.y, q.x, q.y, q.z, smin);
                    }
                }
            }
            #pragma unroll
            for (int off = 8; off; off >>= 1) smin = fminf(smin, __shfl_xor(smin, off, 16));
            best = fminf(best, smin);
            const float rh = (float)R * H;
            if (best <= rh * rh) break;
        }
    }

    // one value per group -> LDS -> per-block partial sum (deterministic)
    __shared__ float red[16];
    if (r == 0) red[threadIdx.x >> 4] = sqrtf(best);
    __syncthreads();
    if (threadIdx.x == 0) {
        float s = 0.0f;
        #pragma unroll
        for (int i = 0; i < 16; ++i) s += red[i];
        bsums[blockIdx.x] = s;
    }
}

// ---------------------------------------------------------------------------
__global__ __launch_bounds__(256) void finalize_kernel(const float* __restrict__ bsums,
                                                       const int* __restrict__ curp,
                                                       float* __restrict__ out) {
    float s = 0.0f;
    for (int i = threadIdx.x; i < 4096; i += 256) s += bsums[i];
    __shared__ float red[256];
    red[threadIdx.x] = s;
    __syncthreads();
    #pragma unroll
    for (int off = 128; off > 0; off >>= 1) {
        if (threadIdx.x < off) red[threadIdx.x] += red[threadIdx.x + off];
        __syncthreads();
    }
    if (threadIdx.x == 0) {
        float decay = powf(1.02f, (float)(curp[0] / 20));
        out[0] = red[0] / 65536.0f * 10.0f / decay;
    }
}

// ---------------------------------------------------------------------------
extern "C" void kernel_launch(void* const* d_in, const int* in_sizes, int n_in,
                              void* d_out, int out_size, void* d_ws, size_t ws_size,
                              hipStream_t stream) {
    const float* target = (const float*)d_in[0];
    const float* outp   = (const float*)d_in[1];
    const int*   cur    = (const int*)d_in[2];
    float*       out    = (float*)d_out;

    // ws layout (~1.3 MB): sortedT | sortedO | cnt | cursor | desc | bsums
    float4* sortedT = (float4*)d_ws;
    float4* sortedO = sortedT + NPTS;
    int*    cnt     = (int*)(sortedO + NPTS);
    int*    cursor  = cnt + 2 * NC;
    int2*   desc    = (int2*)(cursor + 2 * NC);
    float*  bsums   = (float*)(desc + 2 * NC);

    zero_kernel<<<(2 * NC + 255) / 256, 256, 0, stream>>>(cnt);
    hist_kernel<<<256, 256, 0, stream>>>(target, outp, cnt);
    scan_kernel<<<2, 1024, 0, stream>>>(cnt, desc, cursor);
    scatter_kernel<<<256, 256, 0, stream>>>(target, outp, cursor, sortedT, sortedO);
    query_kernel<<<4096, 256, 0, stream>>>(sortedT, sortedO, desc, bsums);
    finalize_kernel<<<1, 256, 0, stream>>>(bsums, cur, out);
}